// Round 24
// baseline (33.912 us; speedup 1.0000x reference)
//
#include <hip/hip_runtime.h>

#define NELL 9
#define CCH  128
#define DB   3
#define P3A  5
#define P2A  3
#define P1A  1
#define P3B  5
#define P2B  2
#define P1B  1
#define NT3  165
#define NT2  45
#define TTOT (NT3 + NT2 + NELL)   // 219 monomials
#define CPB  4                    // c's per block (1 per wave)
#define NCG  (CCH / CPB)          // 32 c-groups per chunk
#define CHR  128                  // rows per chunk (2 per lane)

// Anti-sink fence (r17/r18-proven): ties both accumulators into the asm so
// all prior FMAs must execute before it; memory clobber stops later ds_reads
// hoisting above it. Bounds live ds_read results at one (i,j)-group.
#define ACC_FENCE2(A0, A1) asm volatile("" \
    : "+v"(A0.x), "+v"(A0.y), "+v"(A0.z), "+v"(A0.w), \
      "+v"(A1.x), "+v"(A1.y), "+v"(A1.z), "+v"(A1.w) :: "memory")

// subtractive decoders (<=20 iterations)
__device__ __forceinline__ void dec3(int t, int& i, int& j, int& k) {
    i = 0;
    for (;;) { const int cnt = (9 - i) * (10 - i) / 2; if (t < cnt) break; t -= cnt; i++; }
    j = i;
    for (;;) { const int cnt = 9 - j; if (t < cnt) break; t -= cnt; j++; }
    k = j + t;
}
__device__ __forceinline__ void dec2(int t, int& i, int& j) {
    i = 0;
    for (;;) { const int cnt = 9 - i; if (t < cnt) break; t -= cnt; i++; }
    j = i + t;
}

// bf16 pack (round-to-nearest-even); inputs finite
__device__ __forceinline__ unsigned packbf(float f) {
    const unsigned u = __float_as_uint(f);
    return (u + 0x7FFFu + ((u >> 16) & 1u)) >> 16;
}
__device__ __forceinline__ unsigned packbf2(float lo, float hi) {
    return packbf(lo) | (packbf(hi) << 16);
}

// ws int region (ints):
// [0..3] hdr (0: nchunks), [4 .. 4+MAXCH) chunk_e, [.. +MAXCH) chunk_base,
// [.. +MAXCH) chunk_len, [.. +B) perm, [.. +B) eArr.

// ---------------------------------------------------------------------------
// Build (r22-proven): single block; pass 1 classifies rows from y and caches
// eArr; pass 2 scatters perm from eArr. 128-row chunk descriptors.
// ---------------------------------------------------------------------------
__global__ __launch_bounds__(1024)
void sc_build(const float* __restrict__ y, int B, int E, int MAXCH,
              int* __restrict__ wsi)
{
    __shared__ int cnt[1024];
    __shared__ int off[1024];
    int* chunk_e    = wsi + 4;
    int* chunk_base = wsi + 4 + MAXCH;
    int* chunk_len  = wsi + 4 + 2 * MAXCH;
    int* perm       = wsi + 4 + 3 * MAXCH;
    int* eArr       = wsi + 4 + 3 * MAXCH + B;

    for (int i = threadIdx.x; i < E; i += blockDim.x) cnt[i] = 0;
    __syncthreads();
    for (int b = threadIdx.x; b < B; b += blockDim.x) {
        int e = 0;
        for (int q = 0; q < E; q++) if (y[(size_t)b * E + q] > 0.5f) e = q;
        eArr[b] = e;
        atomicAdd(&cnt[e], 1);
    }
    __syncthreads();
    if (threadIdx.x == 0) {
        int s = 0;
        for (int e = 0; e < E; e++) { off[e] = s; s += cnt[e]; }
        int nch = 0;
        for (int e = 0; e < E; e++)
            for (int i = 0; i < cnt[e]; i += CHR) {
                chunk_e[nch]    = e;
                chunk_base[nch] = off[e] + i;
                chunk_len[nch]  = (cnt[e] - i < CHR) ? (cnt[e] - i) : CHR;
                nch++;
            }
        wsi[0] = nch;
    }
    __syncthreads();
    for (int i = threadIdx.x; i < E; i += blockDim.x) cnt[i] = 0;
    __syncthreads();
    for (int b = threadIdx.x; b < B; b += blockDim.x) {
        const int e = eArr[b];
        const int r = atomicAdd(&cnt[e], 1);
        perm[off[e] + r] = b;
    }
}

// ---------------------------------------------------------------------------
// Main (r22 shape, bf16-packed tile): block = 256 thr = 4 waves; chunk = 128
// same-e rows; lane owns rows (lane, lane+64); wave-uniform c. The 219x4
// tile is computed in f32 during staging (r7 prep order) then RNE-packed to
// bf16 pairs (uint2, 8 B/cell -> broadcast ds_read_b64, half LDS traffic).
// Unpack = shift/mask; 8 f32 FMAs per monomial; ACC_FENCE2 per group.
// ---------------------------------------------------------------------------
__global__ __launch_bounds__(256)
void sc_main_f(const float* __restrict__ x, const int* __restrict__ wsi,
               int MAXCH,
               const float* __restrict__ U3a, const float* __restrict__ U2a,
               const float* __restrict__ U1a, const float* __restrict__ U3b,
               const float* __restrict__ U2b, const float* __restrict__ U1b,
               const float* __restrict__ W3a, const float* __restrict__ W2a,
               const float* __restrict__ W1a, const float* __restrict__ W3b,
               const float* __restrict__ W2b, const float* __restrict__ W1b,
               float* __restrict__ out)
{
    __shared__ uint2 tile[TTOT][CPB];   // 7,008 B (bf16x4 per cell)

    const int chunk = blockIdx.x >> 5;   // / NCG
    const int cgrp  = blockIdx.x & (NCG - 1);
    if (chunk >= wsi[0]) return;

    const int e    = wsi[4 + chunk];
    const int base = wsi[4 + MAXCH + chunk];
    const int len  = wsi[4 + 2 * MAXCH + chunk];
    const int* perm = wsi + 4 + 3 * MAXCH;

    // ---- issue x-gather early (latency overlaps staging below) ----
    const int wv   = threadIdx.x >> 6;   // 0..3 -> c offset (wave-uniform)
    const int lane = threadIdx.x & 63;
    const int c    = cgrp * CPB + wv;

    const bool v0 = (lane < len);
    const bool v1 = (lane + 64 < len);
    const int b0 = perm[base + (v0 ? lane : 0)];
    const int b1 = perm[base + (v1 ? lane + 64 : 0)];

    float xv0[NELL], xv1[NELL];
    const float* xp0 = x + ((size_t)b0 * CCH + c) * NELL;
    const float* xp1 = x + ((size_t)b1 * CCH + c) * NELL;
#pragma unroll
    for (int i = 0; i < NELL; i++) { xv0[i] = xp0[i]; xv1[i] = xp1[i]; }

    // ---- staging: compute fused coefficients (f32, prep-order), pack bf16 --
    for (int idx = threadIdx.x; idx < TTOT * CPB; idx += 256) {
        const int t  = idx >> 2;
        const int cl = idx & (CPB - 1);
        const int cc = cgrp * CPB + cl;
        float v[4] = {0.f, 0.f, 0.f, 0.f};
        if (t < NT3) {
            int i, j, k;
            dec3(t, i, j, k);
            const float mult = (i == k) ? 1.f : ((i == j || j == k) ? 3.f : 6.f);
            const int ijk = (i * 9 + j) * 9 + k;
#pragma unroll
            for (int p = 0; p < P3A; p++)
                v[0] += U3a[ijk * P3A + p] * W3a[(e * P3A + p) * CCH + cc];
#pragma unroll
            for (int d = 0; d < DB; d++)
#pragma unroll
                for (int p = 0; p < P3B; p++)
                    v[1 + d] += U3b[(d * 729 + ijk) * P3B + p] * W3b[(e * P3B + p) * CCH + cc];
#pragma unroll
            for (int d = 0; d < 4; d++) v[d] *= mult;
        } else if (t < NT3 + NT2) {
            int i, j;
            dec2(t - NT3, i, j);
            const float mult = (i == j) ? 1.f : 2.f;
            const int ij = i * 9 + j;
#pragma unroll
            for (int p = 0; p < P2A; p++)
                v[0] += U2a[ij * P2A + p] * W2a[(e * P2A + p) * CCH + cc];
#pragma unroll
            for (int d = 0; d < DB; d++)
#pragma unroll
                for (int p = 0; p < P2B; p++)
                    v[1 + d] += U2b[(d * 81 + ij) * P2B + p] * W2b[(e * P2B + p) * CCH + cc];
#pragma unroll
            for (int d = 0; d < 4; d++) v[d] *= mult;
        } else {
            const int i = t - NT3 - NT2;
            v[0] = U1a[i] * W1a[e * CCH + cc];
#pragma unroll
            for (int d = 0; d < DB; d++)
                v[1 + d] = U1b[d * 9 + i] * W1b[e * CCH + cc];
        }
        uint2 h;
        h.x = packbf2(v[0], v[1]);
        h.y = packbf2(v[2], v[3]);
        tile[t][cl] = h;
    }
    __syncthreads();

    float4 A0 = make_float4(0.f, 0.f, 0.f, 0.f);
    float4 A1 = make_float4(0.f, 0.f, 0.f, 0.f);
    int t = 0;
#pragma unroll
    for (int i = 0; i < NELL; i++) {
#pragma unroll
        for (int j = i; j < NELL; j++) {
            const float p0 = xv0[i] * xv0[j];
            const float p1 = xv1[i] * xv1[j];
#pragma unroll
            for (int k = j; k < NELL; k++) {
                const float m0 = p0 * xv0[k];
                const float m1 = p1 * xv1[k];
                const uint2 hw = tile[t][wv];   // broadcast ds_read_b64
                t++;
                const float wx = __uint_as_float(hw.x << 16);
                const float wy = __uint_as_float(hw.x & 0xFFFF0000u);
                const float wz = __uint_as_float(hw.y << 16);
                const float ww = __uint_as_float(hw.y & 0xFFFF0000u);
                A0.x = fmaf(wx, m0, A0.x);
                A0.y = fmaf(wy, m0, A0.y);
                A0.z = fmaf(wz, m0, A0.z);
                A0.w = fmaf(ww, m0, A0.w);
                A1.x = fmaf(wx, m1, A1.x);
                A1.y = fmaf(wy, m1, A1.y);
                A1.z = fmaf(wz, m1, A1.z);
                A1.w = fmaf(ww, m1, A1.w);
            }
            ACC_FENCE2(A0, A1);                 // FMAs must land; cap live reads
        }
    }
#pragma unroll
    for (int i = 0; i < NELL; i++) {
#pragma unroll
        for (int j = i; j < NELL; j++) {
            const float p0 = xv0[i] * xv0[j];
            const float p1 = xv1[i] * xv1[j];
            const uint2 hw = tile[t][wv];
            t++;
            const float wx = __uint_as_float(hw.x << 16);
            const float wy = __uint_as_float(hw.x & 0xFFFF0000u);
            const float wz = __uint_as_float(hw.y << 16);
            const float ww = __uint_as_float(hw.y & 0xFFFF0000u);
            A0.x = fmaf(wx, p0, A0.x);
            A0.y = fmaf(wy, p0, A0.y);
            A0.z = fmaf(wz, p0, A0.z);
            A0.w = fmaf(ww, p0, A0.w);
            A1.x = fmaf(wx, p1, A1.x);
            A1.y = fmaf(wy, p1, A1.y);
            A1.z = fmaf(wz, p1, A1.z);
            A1.w = fmaf(ww, p1, A1.w);
        }
        ACC_FENCE2(A0, A1);
    }
#pragma unroll
    for (int i = 0; i < NELL; i++) {
        const uint2 hw = tile[t][wv];
        t++;
        const float wx = __uint_as_float(hw.x << 16);
        const float wy = __uint_as_float(hw.x & 0xFFFF0000u);
        const float wz = __uint_as_float(hw.y << 16);
        const float ww = __uint_as_float(hw.y & 0xFFFF0000u);
        A0.x = fmaf(wx, xv0[i], A0.x);
        A0.y = fmaf(wy, xv0[i], A0.y);
        A0.z = fmaf(wz, xv0[i], A0.z);
        A0.w = fmaf(ww, xv0[i], A0.w);
        A1.x = fmaf(wx, xv1[i], A1.x);
        A1.y = fmaf(wy, xv1[i], A1.y);
        A1.z = fmaf(wz, xv1[i], A1.z);
        A1.w = fmaf(ww, xv1[i], A1.w);
    }
    ACC_FENCE2(A0, A1);

    if (v0) {
        float* op = out + (size_t)b0 * (CCH * 4);  // [128 | 384 (c*3+d)]
        op[c] = A0.x;
        op[CCH + c * DB + 0] = A0.y;
        op[CCH + c * DB + 1] = A0.z;
        op[CCH + c * DB + 2] = A0.w;
    }
    if (v1) {
        float* op = out + (size_t)b1 * (CCH * 4);
        op[c] = A1.x;
        op[CCH + c * DB + 0] = A1.y;
        op[CCH + c * DB + 1] = A1.z;
        op[CCH + c * DB + 2] = A1.w;
    }
}

// ---------------------------------------------------------------------------
// Fallback (classification failed or tiny ws): r5-proven direct kernel.
// ---------------------------------------------------------------------------
__global__ __launch_bounds__(CCH)
void sc_direct(const float* __restrict__ x, const float* __restrict__ y, int E,
               const float* __restrict__ U3a, const float* __restrict__ U2a, const float* __restrict__ U1a,
               const float* __restrict__ U3b, const float* __restrict__ U2b, const float* __restrict__ U1b,
               const float* __restrict__ W3a, const float* __restrict__ W2a, const float* __restrict__ W1a,
               const float* __restrict__ W3b, const float* __restrict__ W2b, const float* __restrict__ W1b,
               float* __restrict__ out)
{
    const int c = threadIdx.x;
    const int b = blockIdx.x;

    float xv[NELL];
#pragma unroll
    for (int i = 0; i < NELL; i++) xv[i] = x[(b * CCH + c) * NELL + i];

    int e = 0;
    for (int q = 0; q < E; q++) if (y[b * E + q] > 0.5f) e = q;

    float t3a[P3A] = {}, t3b[DB * P3B] = {};
    float t2a[P2A] = {}, t2b[DB * P2B] = {};
    float t1a = 0.f, t1b[DB] = {};

    for (int i = 0; i < NELL; i++) {
        const float xi = xv[i];
        for (int j = 0; j < NELL; j++) {
            const float xij = xi * xv[j];
            const int ij = i * 9 + j;
#pragma unroll
            for (int p = 0; p < P2A; p++)
                t2a[p] = fmaf(U2a[ij * P2A + p], xij, t2a[p]);
#pragma unroll
            for (int d = 0; d < DB; d++)
#pragma unroll
                for (int p = 0; p < P2B; p++)
                    t2b[d * P2B + p] = fmaf(U2b[(d * 81 + ij) * P2B + p], xij, t2b[d * P2B + p]);
            for (int k = 0; k < NELL; k++) {
                const float m = xij * xv[k];
                const int ijk = ij * 9 + k;
#pragma unroll
                for (int p = 0; p < P3A; p++)
                    t3a[p] = fmaf(U3a[ijk * P3A + p], m, t3a[p]);
#pragma unroll
                for (int d = 0; d < DB; d++)
#pragma unroll
                    for (int p = 0; p < P3B; p++)
                        t3b[d * P3B + p] = fmaf(U3b[(d * 729 + ijk) * P3B + p], m, t3b[d * P3B + p]);
            }
        }
    }
#pragma unroll
    for (int i = 0; i < NELL; i++) {
        t1a = fmaf(U1a[i], xv[i], t1a);
#pragma unroll
        for (int d = 0; d < DB; d++)
            t1b[d] = fmaf(U1b[d * 9 + i], xv[i], t1b[d]);
    }

    float o0 = 0.f;
#pragma unroll
    for (int p = 0; p < P3A; p++) o0 = fmaf(W3a[(e * P3A + p) * CCH + c], t3a[p], o0);
#pragma unroll
    for (int p = 0; p < P2A; p++) o0 = fmaf(W2a[(e * P2A + p) * CCH + c], t2a[p], o0);
    o0 = fmaf(W1a[e * CCH + c], t1a, o0);

    float o1[DB] = {};
#pragma unroll
    for (int p = 0; p < P3B; p++) {
        const float w = W3b[(e * P3B + p) * CCH + c];
#pragma unroll
        for (int d = 0; d < DB; d++) o1[d] = fmaf(w, t3b[d * P3B + p], o1[d]);
    }
#pragma unroll
    for (int p = 0; p < P2B; p++) {
        const float w = W2b[(e * P2B + p) * CCH + c];
#pragma unroll
        for (int d = 0; d < DB; d++) o1[d] = fmaf(w, t2b[d * P2B + p], o1[d]);
    }
    {
        const float w = W1b[e * CCH + c];
#pragma unroll
        for (int d = 0; d < DB; d++) o1[d] = fmaf(w, t1b[d], o1[d]);
    }

    float* op = out + b * (CCH * 4);
    op[c] = o0;
#pragma unroll
    for (int d = 0; d < DB; d++) op[CCH + c * DB + d] = o1[d];
}

extern "C" void kernel_launch(void* const* d_in, const int* in_sizes, int n_in,
                              void* d_out, int out_size, void* d_ws, size_t ws_size,
                              hipStream_t stream)
{
    // ---- order-agnostic classification by element counts (proven r5-r23) ----
    int ix = 0;
    for (int i = 1; i < n_in; i++)
        if (in_sizes[i] > in_sizes[ix]) ix = i;
    int B = in_sizes[ix] / (CCH * NELL);
    bool ok = (n_in == 14) && (B > 0) && (in_sizes[ix] == B * CCH * NELL);

    int iy = -1, E = 0;
    if (ok) {
        for (int i = 0; i < n_in; i++) {
            if (i == ix) continue;
            if (in_sizes[i] % B == 0) {
                int Ec = in_sizes[i] / B;
                if (Ec >= 2 && Ec <= 1024) {
                    if (iy < 0) { iy = i; E = Ec; } else { ok = false; }
                }
            }
        }
        if (iy < 0) ok = false;
    }

    int iU1a = -1, iU2a = -1, iU3a = -1, iU1b = -1, iU2b = -1, iU3b = -1;
    int iW1a = -1, iW1b = -1, iW2a = -1, iW2b = -1, iW3a = -1, iW3b = -1;
    if (ok) {
        for (int i = 0; i < n_in && ok; i++) {
            if (i == ix || i == iy) continue;
            int s = in_sizes[i];
            if      (s == 9 * P1A)        { if (iU1a < 0) iU1a = i; else ok = false; }
            else if (s == 81 * P2A)       { if (iU2a < 0) iU2a = i; else ok = false; }
            else if (s == 729 * P3A)      { if (iU3a < 0) iU3a = i; else ok = false; }
            else if (s == 27 * P1B)       { if (iU1b < 0) iU1b = i; else ok = false; }
            else if (s == 243 * P2B)      { if (iU2b < 0) iU2b = i; else ok = false; }
            else if (s == 2187 * P3B)     { if (iU3b < 0) iU3b = i; else ok = false; }
            else if (s == E * P1A * CCH)  { if (iW1a < 0) iW1a = i; else if (iW1b < 0) iW1b = i; else ok = false; }
            else if (s == E * P2A * CCH)  { if (iW2a < 0) iW2a = i; else ok = false; }
            else if (s == E * P2B * CCH)  { if (iW2b < 0) iW2b = i; else ok = false; }
            else if (s == E * P3A * CCH)  { if (iW3a < 0) iW3a = i; else if (iW3b < 0) iW3b = i; else ok = false; }
            else ok = false;
        }
        if (iU1a < 0 || iU2a < 0 || iU3a < 0 || iU1b < 0 || iU2b < 0 || iU3b < 0 ||
            iW1a < 0 || iW1b < 0 || iW2a < 0 || iW2b < 0 || iW3a < 0 || iW3b < 0)
            ok = false;
    }

    const int MAXCH = (ok ? B / CHR + E + 1 : 1);
    const size_t int_bytes = (size_t)(4 + 3 * MAXCH + 2 * (ok ? B : 1)) * sizeof(int);

    if (ok && ws_size >= int_bytes && B >= 2 && E <= 1024) {
        int* wsi = (int*)d_ws;
        hipLaunchKernelGGL(sc_build, dim3(1), dim3(1024), 0, stream,
                           (const float*)d_in[iy], B, E, MAXCH, wsi);
        hipLaunchKernelGGL(sc_main_f, dim3(MAXCH * NCG), dim3(256), 0, stream,
                           (const float*)d_in[ix], wsi, MAXCH,
                           (const float*)d_in[iU3a], (const float*)d_in[iU2a], (const float*)d_in[iU1a],
                           (const float*)d_in[iU3b], (const float*)d_in[iU2b], (const float*)d_in[iU1b],
                           (const float*)d_in[iW3a], (const float*)d_in[iW2a], (const float*)d_in[iW1a],
                           (const float*)d_in[iW3b], (const float*)d_in[iW2b], (const float*)d_in[iW1b],
                           (float*)d_out);
    } else {
        // dict-order fallback mapping + direct kernel
        if (!ok) {
            ix = 0; iy = 1;
            B = in_sizes[0] / (CCH * NELL);
            E = (B > 0) ? in_sizes[1] / B : 1;
            iU1a = 2;  iW1a = 3;  iU2a = 4;  iW2a = 5;  iU3a = 6;  iW3a = 7;
            iU1b = 8;  iW1b = 9;  iU2b = 10; iW2b = 11; iU3b = 12; iW3b = 13;
        }
        hipLaunchKernelGGL(sc_direct, dim3(B), dim3(CCH), 0, stream,
                           (const float*)d_in[ix], (const float*)d_in[iy], E,
                           (const float*)d_in[iU3a], (const float*)d_in[iU2a], (const float*)d_in[iU1a],
                           (const float*)d_in[iU3b], (const float*)d_in[iU2b], (const float*)d_in[iU1b],
                           (const float*)d_in[iW3a], (const float*)d_in[iW2a], (const float*)d_in[iW1a],
                           (const float*)d_in[iW3b], (const float*)d_in[iW2b], (const float*)d_in[iW1b],
                           (float*)d_out);
    }
}

// Round 25
// 30.368 us; speedup vs baseline: 1.1167x; 1.1167x over previous
//
#include <hip/hip_runtime.h>

#define NELL 9
#define CCH  128
#define DB   3
#define P3A  5
#define P2A  3
#define P1A  1
#define P3B  5
#define P2B  2
#define P1B  1
#define NT3  165
#define NT2  45
#define TTOT (NT3 + NT2 + NELL)   // 219 monomials
#define CPB  4                    // c's per block (1 per wave)
#define NCG  (CCH / CPB)          // 32 c-groups per chunk
#define CHR  128                  // rows per chunk (2 per lane)

// Anti-sink fence (r17/r18-proven): ties both accumulators into the asm so
// all prior FMAs must execute before it; memory clobber stops later ds_reads
// hoisting above it. Bounds live ds_read results at one (i,j)-group.
#define ACC_FENCE2(A0, A1) asm volatile("" \
    : "+v"(A0.x), "+v"(A0.y), "+v"(A0.z), "+v"(A0.w), \
      "+v"(A1.x), "+v"(A1.y), "+v"(A1.z), "+v"(A1.w) :: "memory")

// subtractive decoders (<=20 iterations)
__device__ __forceinline__ void dec3(int t, int& i, int& j, int& k) {
    i = 0;
    for (;;) { const int cnt = (9 - i) * (10 - i) / 2; if (t < cnt) break; t -= cnt; i++; }
    j = i;
    for (;;) { const int cnt = 9 - j; if (t < cnt) break; t -= cnt; j++; }
    k = j + t;
}
__device__ __forceinline__ void dec2(int t, int& i, int& j) {
    i = 0;
    for (;;) { const int cnt = 9 - i; if (t < cnt) break; t -= cnt; i++; }
    j = i + t;
}

// ws int region (ints):
// [0..3] hdr (0: nchunks), [4 .. 4+MAXCH) chunk_e, [.. +MAXCH) chunk_base,
// [.. +MAXCH) chunk_len, [.. +B) perm, [.. +B) eArr.

// ---------------------------------------------------------------------------
// Build (r22-proven): single block; pass 1 classifies rows from y and caches
// eArr; pass 2 scatters perm from eArr. 128-row chunk descriptors.
// ---------------------------------------------------------------------------
__global__ __launch_bounds__(1024)
void sc_build(const float* __restrict__ y, int B, int E, int MAXCH,
              int* __restrict__ wsi)
{
    __shared__ int cnt[1024];
    __shared__ int off[1024];
    int* chunk_e    = wsi + 4;
    int* chunk_base = wsi + 4 + MAXCH;
    int* chunk_len  = wsi + 4 + 2 * MAXCH;
    int* perm       = wsi + 4 + 3 * MAXCH;
    int* eArr       = wsi + 4 + 3 * MAXCH + B;

    for (int i = threadIdx.x; i < E; i += blockDim.x) cnt[i] = 0;
    __syncthreads();
    for (int b = threadIdx.x; b < B; b += blockDim.x) {
        int e = 0;
        for (int q = 0; q < E; q++) if (y[(size_t)b * E + q] > 0.5f) e = q;
        eArr[b] = e;
        atomicAdd(&cnt[e], 1);
    }
    __syncthreads();
    if (threadIdx.x == 0) {
        int s = 0;
        for (int e = 0; e < E; e++) { off[e] = s; s += cnt[e]; }
        int nch = 0;
        for (int e = 0; e < E; e++)
            for (int i = 0; i < cnt[e]; i += CHR) {
                chunk_e[nch]    = e;
                chunk_base[nch] = off[e] + i;
                chunk_len[nch]  = (cnt[e] - i < CHR) ? (cnt[e] - i) : CHR;
                nch++;
            }
        wsi[0] = nch;
    }
    __syncthreads();
    for (int i = threadIdx.x; i < E; i += blockDim.x) cnt[i] = 0;
    __syncthreads();
    for (int b = threadIdx.x; b < B; b += blockDim.x) {
        const int e = eArr[b];
        const int r = atomicAdd(&cnt[e], 1);
        perm[off[e] + r] = b;
    }
}

// ---------------------------------------------------------------------------
// Main (r22-proven): block = 256 thr = 4 waves; chunk = 128 same-e rows;
// lane owns rows (lane, lane+64); wave-uniform c (cgrp*4+wv). The 219x4
// float4 tile (14 KB) is computed during staging (bit-identical to r7 prep
// order). x-gather issued early. Broadcast ds_read_b128 feeds 8 FMAs;
// ACC_FENCE2 per group stops load-hoist spill.
// ---------------------------------------------------------------------------
__global__ __launch_bounds__(256)
void sc_main_f(const float* __restrict__ x, const int* __restrict__ wsi,
               int MAXCH,
               const float* __restrict__ U3a, const float* __restrict__ U2a,
               const float* __restrict__ U1a, const float* __restrict__ U3b,
               const float* __restrict__ U2b, const float* __restrict__ U1b,
               const float* __restrict__ W3a, const float* __restrict__ W2a,
               const float* __restrict__ W1a, const float* __restrict__ W3b,
               const float* __restrict__ W2b, const float* __restrict__ W1b,
               float* __restrict__ out)
{
    __shared__ float4 tile[TTOT][CPB];   // 14,016 B

    const int chunk = blockIdx.x >> 5;   // / NCG
    const int cgrp  = blockIdx.x & (NCG - 1);
    if (chunk >= wsi[0]) return;

    const int e    = wsi[4 + chunk];
    const int base = wsi[4 + MAXCH + chunk];
    const int len  = wsi[4 + 2 * MAXCH + chunk];
    const int* perm = wsi + 4 + 3 * MAXCH;

    // ---- issue x-gather early (latency overlaps staging below) ----
    const int wv   = threadIdx.x >> 6;   // 0..3 -> c offset (wave-uniform)
    const int lane = threadIdx.x & 63;
    const int c    = cgrp * CPB + wv;

    const bool v0 = (lane < len);
    const bool v1 = (lane + 64 < len);
    const int b0 = perm[base + (v0 ? lane : 0)];
    const int b1 = perm[base + (v1 ? lane + 64 : 0)];

    float xv0[NELL], xv1[NELL];
    const float* xp0 = x + ((size_t)b0 * CCH + c) * NELL;
    const float* xp1 = x + ((size_t)b1 * CCH + c) * NELL;
#pragma unroll
    for (int i = 0; i < NELL; i++) { xv0[i] = xp0[i]; xv1[i] = xp1[i]; }

    // ---- staging: compute fused coefficients directly (prep inlined) ----
    for (int idx = threadIdx.x; idx < TTOT * CPB; idx += 256) {
        const int t  = idx >> 2;
        const int cl = idx & (CPB - 1);
        const int cc = cgrp * CPB + cl;
        float v[4] = {0.f, 0.f, 0.f, 0.f};
        if (t < NT3) {
            int i, j, k;
            dec3(t, i, j, k);
            const float mult = (i == k) ? 1.f : ((i == j || j == k) ? 3.f : 6.f);
            const int ijk = (i * 9 + j) * 9 + k;
#pragma unroll
            for (int p = 0; p < P3A; p++)
                v[0] += U3a[ijk * P3A + p] * W3a[(e * P3A + p) * CCH + cc];
#pragma unroll
            for (int d = 0; d < DB; d++)
#pragma unroll
                for (int p = 0; p < P3B; p++)
                    v[1 + d] += U3b[(d * 729 + ijk) * P3B + p] * W3b[(e * P3B + p) * CCH + cc];
#pragma unroll
            for (int d = 0; d < 4; d++) v[d] *= mult;
        } else if (t < NT3 + NT2) {
            int i, j;
            dec2(t - NT3, i, j);
            const float mult = (i == j) ? 1.f : 2.f;
            const int ij = i * 9 + j;
#pragma unroll
            for (int p = 0; p < P2A; p++)
                v[0] += U2a[ij * P2A + p] * W2a[(e * P2A + p) * CCH + cc];
#pragma unroll
            for (int d = 0; d < DB; d++)
#pragma unroll
                for (int p = 0; p < P2B; p++)
                    v[1 + d] += U2b[(d * 81 + ij) * P2B + p] * W2b[(e * P2B + p) * CCH + cc];
#pragma unroll
            for (int d = 0; d < 4; d++) v[d] *= mult;
        } else {
            const int i = t - NT3 - NT2;
            v[0] = U1a[i] * W1a[e * CCH + cc];
#pragma unroll
            for (int d = 0; d < DB; d++)
                v[1 + d] = U1b[d * 9 + i] * W1b[e * CCH + cc];
        }
        tile[t][cl] = make_float4(v[0], v[1], v[2], v[3]);
    }
    __syncthreads();

    float4 A0 = make_float4(0.f, 0.f, 0.f, 0.f);
    float4 A1 = make_float4(0.f, 0.f, 0.f, 0.f);
    int t = 0;
#pragma unroll
    for (int i = 0; i < NELL; i++) {
#pragma unroll
        for (int j = i; j < NELL; j++) {
            const float p0 = xv0[i] * xv0[j];
            const float p1 = xv1[i] * xv1[j];
#pragma unroll
            for (int k = j; k < NELL; k++) {
                const float m0 = p0 * xv0[k];
                const float m1 = p1 * xv1[k];
                const float4 w = tile[t][wv];   // broadcast ds_read_b128
                t++;
                A0.x = fmaf(w.x, m0, A0.x);
                A0.y = fmaf(w.y, m0, A0.y);
                A0.z = fmaf(w.z, m0, A0.z);
                A0.w = fmaf(w.w, m0, A0.w);
                A1.x = fmaf(w.x, m1, A1.x);
                A1.y = fmaf(w.y, m1, A1.y);
                A1.z = fmaf(w.z, m1, A1.z);
                A1.w = fmaf(w.w, m1, A1.w);
            }
            ACC_FENCE2(A0, A1);                 // FMAs must land; cap live reads
        }
    }
#pragma unroll
    for (int i = 0; i < NELL; i++) {
#pragma unroll
        for (int j = i; j < NELL; j++) {
            const float p0 = xv0[i] * xv0[j];
            const float p1 = xv1[i] * xv1[j];
            const float4 w = tile[t][wv];
            t++;
            A0.x = fmaf(w.x, p0, A0.x);
            A0.y = fmaf(w.y, p0, A0.y);
            A0.z = fmaf(w.z, p0, A0.z);
            A0.w = fmaf(w.w, p0, A0.w);
            A1.x = fmaf(w.x, p1, A1.x);
            A1.y = fmaf(w.y, p1, A1.y);
            A1.z = fmaf(w.z, p1, A1.z);
            A1.w = fmaf(w.w, p1, A1.w);
        }
        ACC_FENCE2(A0, A1);
    }
#pragma unroll
    for (int i = 0; i < NELL; i++) {
        const float4 w = tile[t][wv];
        t++;
        A0.x = fmaf(w.x, xv0[i], A0.x);
        A0.y = fmaf(w.y, xv0[i], A0.y);
        A0.z = fmaf(w.z, xv0[i], A0.z);
        A0.w = fmaf(w.w, xv0[i], A0.w);
        A1.x = fmaf(w.x, xv1[i], A1.x);
        A1.y = fmaf(w.y, xv1[i], A1.y);
        A1.z = fmaf(w.z, xv1[i], A1.z);
        A1.w = fmaf(w.w, xv1[i], A1.w);
    }
    ACC_FENCE2(A0, A1);

    if (v0) {
        float* op = out + (size_t)b0 * (CCH * 4);  // [128 | 384 (c*3+d)]
        op[c] = A0.x;
        op[CCH + c * DB + 0] = A0.y;
        op[CCH + c * DB + 1] = A0.z;
        op[CCH + c * DB + 2] = A0.w;
    }
    if (v1) {
        float* op = out + (size_t)b1 * (CCH * 4);
        op[c] = A1.x;
        op[CCH + c * DB + 0] = A1.y;
        op[CCH + c * DB + 1] = A1.z;
        op[CCH + c * DB + 2] = A1.w;
    }
}

// ---------------------------------------------------------------------------
// Fallback (classification failed or tiny ws): r5-proven direct kernel.
// ---------------------------------------------------------------------------
__global__ __launch_bounds__(CCH)
void sc_direct(const float* __restrict__ x, const float* __restrict__ y, int E,
               const float* __restrict__ U3a, const float* __restrict__ U2a, const float* __restrict__ U1a,
               const float* __restrict__ U3b, const float* __restrict__ U2b, const float* __restrict__ U1b,
               const float* __restrict__ W3a, const float* __restrict__ W2a, const float* __restrict__ W1a,
               const float* __restrict__ W3b, const float* __restrict__ W2b, const float* __restrict__ W1b,
               float* __restrict__ out)
{
    const int c = threadIdx.x;
    const int b = blockIdx.x;

    float xv[NELL];
#pragma unroll
    for (int i = 0; i < NELL; i++) xv[i] = x[(b * CCH + c) * NELL + i];

    int e = 0;
    for (int q = 0; q < E; q++) if (y[b * E + q] > 0.5f) e = q;

    float t3a[P3A] = {}, t3b[DB * P3B] = {};
    float t2a[P2A] = {}, t2b[DB * P2B] = {};
    float t1a = 0.f, t1b[DB] = {};

    for (int i = 0; i < NELL; i++) {
        const float xi = xv[i];
        for (int j = 0; j < NELL; j++) {
            const float xij = xi * xv[j];
            const int ij = i * 9 + j;
#pragma unroll
            for (int p = 0; p < P2A; p++)
                t2a[p] = fmaf(U2a[ij * P2A + p], xij, t2a[p]);
#pragma unroll
            for (int d = 0; d < DB; d++)
#pragma unroll
                for (int p = 0; p < P2B; p++)
                    t2b[d * P2B + p] = fmaf(U2b[(d * 81 + ij) * P2B + p], xij, t2b[d * P2B + p]);
            for (int k = 0; k < NELL; k++) {
                const float m = xij * xv[k];
                const int ijk = ij * 9 + k;
#pragma unroll
                for (int p = 0; p < P3A; p++)
                    t3a[p] = fmaf(U3a[ijk * P3A + p], m, t3a[p]);
#pragma unroll
                for (int d = 0; d < DB; d++)
#pragma unroll
                    for (int p = 0; p < P3B; p++)
                        t3b[d * P3B + p] = fmaf(U3b[(d * 729 + ijk) * P3B + p], m, t3b[d * P3B + p]);
            }
        }
    }
#pragma unroll
    for (int i = 0; i < NELL; i++) {
        t1a = fmaf(U1a[i], xv[i], t1a);
#pragma unroll
        for (int d = 0; d < DB; d++)
            t1b[d] = fmaf(U1b[d * 9 + i], xv[i], t1b[d]);
    }

    float o0 = 0.f;
#pragma unroll
    for (int p = 0; p < P3A; p++) o0 = fmaf(W3a[(e * P3A + p) * CCH + c], t3a[p], o0);
#pragma unroll
    for (int p = 0; p < P2A; p++) o0 = fmaf(W2a[(e * P2A + p) * CCH + c], t2a[p], o0);
    o0 = fmaf(W1a[e * CCH + c], t1a, o0);

    float o1[DB] = {};
#pragma unroll
    for (int p = 0; p < P3B; p++) {
        const float w = W3b[(e * P3B + p) * CCH + c];
#pragma unroll
        for (int d = 0; d < DB; d++) o1[d] = fmaf(w, t3b[d * P3B + p], o1[d]);
    }
#pragma unroll
    for (int p = 0; p < P2B; p++) {
        const float w = W2b[(e * P2B + p) * CCH + c];
#pragma unroll
        for (int d = 0; d < DB; d++) o1[d] = fmaf(w, t2b[d * P2B + p], o1[d]);
    }
    {
        const float w = W1b[e * CCH + c];
#pragma unroll
        for (int d = 0; d < DB; d++) o1[d] = fmaf(w, t1b[d], o1[d]);
    }

    float* op = out + b * (CCH * 4);
    op[c] = o0;
#pragma unroll
    for (int d = 0; d < DB; d++) op[CCH + c * DB + d] = o1[d];
}

extern "C" void kernel_launch(void* const* d_in, const int* in_sizes, int n_in,
                              void* d_out, int out_size, void* d_ws, size_t ws_size,
                              hipStream_t stream)
{
    // ---- order-agnostic classification by element counts (proven r5-r24) ----
    int ix = 0;
    for (int i = 1; i < n_in; i++)
        if (in_sizes[i] > in_sizes[ix]) ix = i;
    int B = in_sizes[ix] / (CCH * NELL);
    bool ok = (n_in == 14) && (B > 0) && (in_sizes[ix] == B * CCH * NELL);

    int iy = -1, E = 0;
    if (ok) {
        for (int i = 0; i < n_in; i++) {
            if (i == ix) continue;
            if (in_sizes[i] % B == 0) {
                int Ec = in_sizes[i] / B;
                if (Ec >= 2 && Ec <= 1024) {
                    if (iy < 0) { iy = i; E = Ec; } else { ok = false; }
                }
            }
        }
        if (iy < 0) ok = false;
    }

    int iU1a = -1, iU2a = -1, iU3a = -1, iU1b = -1, iU2b = -1, iU3b = -1;
    int iW1a = -1, iW1b = -1, iW2a = -1, iW2b = -1, iW3a = -1, iW3b = -1;
    if (ok) {
        for (int i = 0; i < n_in && ok; i++) {
            if (i == ix || i == iy) continue;
            int s = in_sizes[i];
            if      (s == 9 * P1A)        { if (iU1a < 0) iU1a = i; else ok = false; }
            else if (s == 81 * P2A)       { if (iU2a < 0) iU2a = i; else ok = false; }
            else if (s == 729 * P3A)      { if (iU3a < 0) iU3a = i; else ok = false; }
            else if (s == 27 * P1B)       { if (iU1b < 0) iU1b = i; else ok = false; }
            else if (s == 243 * P2B)      { if (iU2b < 0) iU2b = i; else ok = false; }
            else if (s == 2187 * P3B)     { if (iU3b < 0) iU3b = i; else ok = false; }
            else if (s == E * P1A * CCH)  { if (iW1a < 0) iW1a = i; else if (iW1b < 0) iW1b = i; else ok = false; }
            else if (s == E * P2A * CCH)  { if (iW2a < 0) iW2a = i; else ok = false; }
            else if (s == E * P2B * CCH)  { if (iW2b < 0) iW2b = i; else ok = false; }
            else if (s == E * P3A * CCH)  { if (iW3a < 0) iW3a = i; else if (iW3b < 0) iW3b = i; else ok = false; }
            else ok = false;
        }
        if (iU1a < 0 || iU2a < 0 || iU3a < 0 || iU1b < 0 || iU2b < 0 || iU3b < 0 ||
            iW1a < 0 || iW1b < 0 || iW2a < 0 || iW2b < 0 || iW3a < 0 || iW3b < 0)
            ok = false;
    }

    const int MAXCH = (ok ? B / CHR + E + 1 : 1);
    const size_t int_bytes = (size_t)(4 + 3 * MAXCH + 2 * (ok ? B : 1)) * sizeof(int);

    if (ok && ws_size >= int_bytes && B >= 2 && E <= 1024) {
        int* wsi = (int*)d_ws;
        hipLaunchKernelGGL(sc_build, dim3(1), dim3(1024), 0, stream,
                           (const float*)d_in[iy], B, E, MAXCH, wsi);
        hipLaunchKernelGGL(sc_main_f, dim3(MAXCH * NCG), dim3(256), 0, stream,
                           (const float*)d_in[ix], wsi, MAXCH,
                           (const float*)d_in[iU3a], (const float*)d_in[iU2a], (const float*)d_in[iU1a],
                           (const float*)d_in[iU3b], (const float*)d_in[iU2b], (const float*)d_in[iU1b],
                           (const float*)d_in[iW3a], (const float*)d_in[iW2a], (const float*)d_in[iW1a],
                           (const float*)d_in[iW3b], (const float*)d_in[iW2b], (const float*)d_in[iW1b],
                           (float*)d_out);
    } else {
        // dict-order fallback mapping + direct kernel
        if (!ok) {
            ix = 0; iy = 1;
            B = in_sizes[0] / (CCH * NELL);
            E = (B > 0) ? in_sizes[1] / B : 1;
            iU1a = 2;  iW1a = 3;  iU2a = 4;  iW2a = 5;  iU3a = 6;  iW3a = 7;
            iU1b = 8;  iW1b = 9;  iU2b = 10; iW2b = 11; iU3b = 12; iW3b = 13;
        }
        hipLaunchKernelGGL(sc_direct, dim3(B), dim3(CCH), 0, stream,
                           (const float*)d_in[ix], (const float*)d_in[iy], E,
                           (const float*)d_in[iU3a], (const float*)d_in[iU2a], (const float*)d_in[iU1a],
                           (const float*)d_in[iU3b], (const float*)d_in[iU2b], (const float*)d_in[iU1b],
                           (const float*)d_in[iW3a], (const float*)d_in[iW2a], (const float*)d_in[iW1a],
                           (const float*)d_in[iW3b], (const float*)d_in[iW2b], (const float*)d_in[iW1b],
                           (float*)d_out);
    }
}